// Round 1
// baseline (199.682 us; speedup 1.0000x reference)
//
#include <hip/hip_runtime.h>
#include <hip/hip_bf16.h>
#include <cmath>

typedef __bf16 bf16;
typedef __bf16 bf16x8 __attribute__((ext_vector_type(8)));
typedef __bf16 bf16x4 __attribute__((ext_vector_type(4)));
typedef float f32x4 __attribute__((ext_vector_type(4)));

#define QS 0.18033688f   // hd^-0.5 * log2(e), folded into Wq/bq

// async 16B global->LDS. LDS dest = wave-uniform base + lane*16.
__device__ __forceinline__ void load16_to_lds(const void* g, void* l) {
    __builtin_amdgcn_global_load_lds(
        (const __attribute__((address_space(1))) unsigned int*)g,
        (__attribute__((address_space(3))) unsigned int*)l, 16, 0, 0);
}

// ---------------------------------------------------------------------------
// f32 -> bf16 convert: [x(4M) | Wq(1M) | Wk(1M) | Wv(1M) | Wo(1M)] -> dst
// Wq segment is prescaled by QS (softmax scale folded into Q projection).
// ---------------------------------------------------------------------------
__global__ __launch_bounds__(256) void convert_kernel(
    const float* __restrict__ x,  const float* __restrict__ wq,
    const float* __restrict__ wk, const float* __restrict__ wv,
    const float* __restrict__ wo, bf16* __restrict__ dst)
{
    const size_t M1 = 1024ull * 1024ull, M4 = 4ull * M1;
    size_t i0 = ((size_t)blockIdx.x * 256 + threadIdx.x) * 8;
    const float* s;
    size_t off;
    float sc = 1.f;
    if      (i0 < M4)        { s = x;  off = i0; }
    else if (i0 < M4 + M1)   { s = wq; off = i0 - M4; sc = QS; }
    else if (i0 < M4 + 2*M1) { s = wk; off = i0 - M4 - M1; }
    else if (i0 < M4 + 3*M1) { s = wv; off = i0 - M4 - 2*M1; }
    else                     { s = wo; off = i0 - M4 - 3*M1; }
    float4 a = *(const float4*)(s + off);
    float4 b = *(const float4*)(s + off + 4);
    bf16x8 r = { (bf16)(a.x*sc), (bf16)(a.y*sc), (bf16)(a.z*sc), (bf16)(a.w*sc),
                 (bf16)(b.x*sc), (bf16)(b.y*sc), (bf16)(b.z*sc), (bf16)(b.w*sc) };
    *(bf16x8*)(dst + i0) = r;
}

// ---------------------------------------------------------------------------
// bf16 GEMM, m97 structure: BK=32, 16B global_load_lds, XOR-swizzled LDS.
// BM=128: 4 waves 2x2 of 64x64 (acc[4][4]); BM=64: 2x2 of 32x64 (acc[2][4]).
// ---------------------------------------------------------------------------
template<int BM, bool OUT_F32>
__device__ __forceinline__ void gemm_core(
    const bf16* __restrict__ A, const bf16* __restrict__ W,
    const float* __restrict__ bias, void* __restrict__ C,
    int mb, int nb, bool vt_out, float bias_scale)
{
    constexpr int IF = BM / 32;
    __shared__ __align__(16) bf16 As[BM * 32];
    __shared__ __align__(16) bf16 Bs[128 * 32];

    const int tid  = threadIdx.x;
    const int lane = tid & 63;
    const int wave = tid >> 6;
    const int wr   = (wave >> 1) * (BM / 2);
    const int wc   = (wave & 1) * 64;
    const int l15  = lane & 15;
    const int l4   = lane >> 4;
    const int swz  = (l4 ^ ((l15 >> 1) & 3)) * 8;   // swizzled read column

    f32x4 acc[IF][4] = {};

    for (int kt = 0; kt < 32; ++kt) {
#pragma unroll
        for (int it = 0; it < BM / 64; ++it) {
            int c = it * 256 + tid;
            int scol = ((c & 3) ^ ((c >> 3) & 3)) * 8;
            load16_to_lds(&A[(size_t)(mb * BM + (c >> 2)) * 1024 + kt * 32 + scol],
                          &As[(it * 256 + (tid & 192)) * 8]);
        }
#pragma unroll
        for (int it = 0; it < 2; ++it) {
            int c = it * 256 + tid;
            int scol = ((c & 3) ^ ((c >> 3) & 3)) * 8;
            load16_to_lds(&W[(size_t)(nb * 128 + (c >> 2)) * 1024 + kt * 32 + scol],
                          &Bs[(it * 256 + (tid & 192)) * 8]);
        }
        __syncthreads();
        bf16x8 af[IF], bfr[4];
#pragma unroll
        for (int i = 0; i < IF; ++i)
            af[i] = *(const bf16x8*)&As[(wr + i * 16 + l15) * 32 + swz];
#pragma unroll
        for (int j = 0; j < 4; ++j)
            bfr[j] = *(const bf16x8*)&Bs[(wc + j * 16 + l15) * 32 + swz];
#pragma unroll
        for (int i = 0; i < IF; ++i)
#pragma unroll
            for (int j = 0; j < 4; ++j)
                acc[i][j] = __builtin_amdgcn_mfma_f32_16x16x32_bf16(
                    af[i], bfr[j], acc[i][j], 0, 0, 0);
        __syncthreads();
    }

    if (!OUT_F32 && vt_out) {
        // V output transposed: vt[(b*16+h)*64+d][s]
#pragma unroll
        for (int j = 0; j < 4; ++j) {
            int col = nb * 128 + wc + j * 16 + l15;
            float bv = bias ? bias[col] : 0.f;
            int h = col >> 6, d = col & 63;
#pragma unroll
            for (int i = 0; i < IF; ++i) {
                int m0 = mb * BM + wr + i * 16 + l4 * 4;
                int b = m0 >> 11, s = m0 & 2047;
                bf16x4 pk = { (bf16)(acc[i][j][0] + bv), (bf16)(acc[i][j][1] + bv),
                              (bf16)(acc[i][j][2] + bv), (bf16)(acc[i][j][3] + bv) };
                *(bf16x4*)&((bf16*)C)[(size_t)((b * 16 + h) * 64 + d) * 2048 + s] = pk;
            }
        }
    } else {
#pragma unroll
        for (int j = 0; j < 4; ++j) {
            int col = nb * 128 + wc + j * 16 + l15;
            float bv = bias ? bias[col] * bias_scale : 0.f;
#pragma unroll
            for (int i = 0; i < IF; ++i) {
                int row0 = mb * BM + wr + i * 16 + l4 * 4;
#pragma unroll
                for (int r = 0; r < 4; ++r) {
                    float val = acc[i][j][r] + bv;
                    size_t idx = (size_t)(row0 + r) * 1024 + col;
                    if (OUT_F32) ((float*)C)[idx] = val;
                    else         ((bf16*)C)[idx]  = (bf16)val;
                }
            }
        }
    }
}

__global__ __launch_bounds__(256) void qkv_kernel(
    const bf16* __restrict__ xb,
    const bf16* __restrict__ wqb, const float* __restrict__ bq,
    const bf16* __restrict__ wkb,
    const bf16* __restrict__ wvb, const float* __restrict__ bv,
    bf16* __restrict__ q, bf16* __restrict__ k, bf16* __restrict__ vt)
{
    int mb = blockIdx.x;
    int nbg = blockIdx.y;
    int sel = nbg >> 3, nb = nbg & 7;
    const bf16* W = (sel == 0) ? wqb : ((sel == 1) ? wkb : wvb);
    const float* bias = (sel == 0) ? bq : ((sel == 2) ? bv : nullptr);
    bf16* C = (sel == 0) ? q : ((sel == 1) ? k : vt);
    gemm_core<128, false>(xb, W, bias, C, mb, nb, sel == 2,
                          sel == 0 ? QS : 1.f);
}

__global__ __launch_bounds__(256) void oproj_kernel(
    const bf16* __restrict__ ao, const bf16* __restrict__ wob,
    const float* __restrict__ bo, float* __restrict__ out)
{
    // BM=128: 2x MFMA per LDS fragment byte vs BM=64 (same code path as qkv)
    gemm_core<128, true>(ao, wob, bo, out, blockIdx.x, blockIdx.y, false, 1.f);
}

// ---------------------------------------------------------------------------
// Flash attention, S^T form, fixed-max softmax (p = 2^s, scores bounded).
// Q prescaled (QS folded into Wq/bq).
//
// v2 restructure: 128-row q-tiles, 32 q-rows per wave (2 B-fragments).
// Each K/V LDS A-fragment read now feeds TWO MFMAs -> K/V LDS traffic per
// unit of q*k work halves; barriers per q-row halve (34 iters/block).
// Paired q-tiles (t, 15-t): uniform 34 key-tile iters for all 256 blocks.
// Grid = (bh, pair) so all blocks of one (b,h) land on the same XCD
// (linear%8 == bh%8) -> K/V stay in one L2.
// Double-buffered, XOR-swizzled K/VT staging; mask only on last two tiles;
// fully-masked last tile skipped per-wave; l-sum deferred to epilogue.
// ---------------------------------------------------------------------------
__global__ __launch_bounds__(256) void attn_kernel(
    const bf16* __restrict__ q, const bf16* __restrict__ k,
    const bf16* __restrict__ vt, bf16* __restrict__ o)
{
    __shared__ __align__(16) bf16 Ks[2][64 * 64];   // [key][d] swizzled
    __shared__ __align__(16) bf16 Vs[2][64 * 64];   // [d][key] swizzled
    __shared__ __align__(16) bf16 Ps[4][32 * 72];   // per-wave [q][key], stride 72

    const int tid  = threadIdx.x;
    const int lane = tid & 63;
    const int wave = tid >> 6;
    const int l15  = lane & 15;
    const int l4   = lane >> 4;

    const int bh = blockIdx.x;               // fast dim -> XCD = bh % 8
    const int pairIdx = blockIdx.y;          // 0..7
    const int b = bh >> 4, h = bh & 15;
    const int qts[2] = { pairIdx, 15 - pairIdx };

    auto stage = [&](int nt, int buf) {
#pragma unroll
        for (int it = 0; it < 2; ++it) {
            int c = it * 256 + tid;
            int scol = ((c & 7) ^ ((c >> 3) & 7)) * 8;
            load16_to_lds(&k[(size_t)(b * 2048 + nt * 64 + (c >> 3)) * 1024 + h * 64 + scol],
                          &Ks[buf][(it * 256 + (tid & 192)) * 8]);
            load16_to_lds(&vt[(size_t)(bh * 64 + (c >> 3)) * 2048 + nt * 64 + scol],
                          &Vs[buf][(it * 256 + (tid & 192)) * 8]);
        }
    };

    int b0 = 0;
    stage(0, 0);

    for (int seg = 0; seg < 2; ++seg) {
        const int qt = qts[seg];                    // q128-tile index, 0..15
        const int qrow0 = qt * 128 + wave * 32;     // wave's first q row
        bf16x8 qf[2][2];
#pragma unroll
        for (int qb = 0; qb < 2; ++qb)
#pragma unroll
            for (int kk = 0; kk < 2; ++kk)
                qf[qb][kk] = *(const bf16x8*)&q[(size_t)(b * 2048 + qrow0 + qb * 16 + l15) * 1024
                                               + h * 64 + kk * 32 + l4 * 8];

        f32x4 oacc[2][4] = {};
        float lsum[2] = { 0.f, 0.f };

        const int n = 2 * qt + 2;
        for (int nt = 0; nt < n; ++nt) {
            __syncthreads();                        // stage(nt) drained
            if (nt + 1 < n)      stage(nt + 1, b0 ^ 1);
            else if (seg == 0)   stage(0, b0 ^ 1);  // first tile of segment 2

            // per-wave skip: tile entirely above the causal diagonal
            if (nt * 64 > qrow0 + 31) { b0 ^= 1; continue; }

            // St[key][q] = K · Q^T, two q-fragments per K-fragment read
            f32x4 s[2][4] = {};
#pragma unroll
            for (int kk = 0; kk < 2; ++kk) {
#pragma unroll
                for (int j = 0; j < 4; ++j) {
                    bf16x8 kf = *(const bf16x8*)&Ks[b0][(j * 16 + l15) * 64
                                    + (((kk * 4 + l4) ^ (l15 & 7)) * 8)];
                    s[0][j] = __builtin_amdgcn_mfma_f32_16x16x32_bf16(kf, qf[0][kk], s[0][j], 0, 0, 0);
                    s[1][j] = __builtin_amdgcn_mfma_f32_16x16x32_bf16(kf, qf[1][kk], s[1][j], 0, 0, 0);
                }
            }

            // fixed-max: p = 2^s; mask only where the tile crosses the diagonal
            const bool diag = (nt >= 2 * qt);
#pragma unroll
            for (int qb = 0; qb < 2; ++qb) {
                float pv[4][4];
                if (diag) {
                    int qg = qrow0 + qb * 16 + l15;
#pragma unroll
                    for (int j = 0; j < 4; ++j)
#pragma unroll
                        for (int r = 0; r < 4; ++r) {
                            int kg = nt * 64 + j * 16 + l4 * 4 + r;
                            pv[j][r] = (kg > qg) ? 0.f : __builtin_amdgcn_exp2f(s[qb][j][r]);
                        }
                } else {
#pragma unroll
                    for (int j = 0; j < 4; ++j)
#pragma unroll
                        for (int r = 0; r < 4; ++r)
                            pv[j][r] = __builtin_amdgcn_exp2f(s[qb][j][r]);
                }
#pragma unroll
                for (int j = 0; j < 4; ++j)
                    lsum[qb] += (pv[j][0] + pv[j][1]) + (pv[j][2] + pv[j][3]);

                // P^T (C-layout) -> Ps[q][key] (A-layout); wave-private
#pragma unroll
                for (int j = 0; j < 4; ++j) {
                    bf16x4 pk = { (bf16)pv[j][0], (bf16)pv[j][1], (bf16)pv[j][2], (bf16)pv[j][3] };
                    *(bf16x4*)&Ps[wave][(qb * 16 + l15) * 72 + j * 16 + l4 * 4] = pk;
                }
            }

            // O += P · V, two P-fragments per V-fragment read
#pragma unroll
            for (int kk = 0; kk < 2; ++kk) {
                bf16x8 pf0 = *(const bf16x8*)&Ps[wave][l15 * 72 + kk * 32 + l4 * 8];
                bf16x8 pf1 = *(const bf16x8*)&Ps[wave][(16 + l15) * 72 + kk * 32 + l4 * 8];
#pragma unroll
                for (int f = 0; f < 4; ++f) {
                    bf16x8 vf = *(const bf16x8*)&Vs[b0][(f * 16 + l15) * 64
                                    + (((kk * 4 + l4) ^ (l15 & 7)) * 8)];
                    oacc[0][f] = __builtin_amdgcn_mfma_f32_16x16x32_bf16(pf0, vf, oacc[0][f], 0, 0, 0);
                    oacc[1][f] = __builtin_amdgcn_mfma_f32_16x16x32_bf16(pf1, vf, oacc[1][f], 0, 0, 0);
                }
            }
            b0 ^= 1;
        }

        // epilogue: reduce l across the 4 l4-groups, divide, store
#pragma unroll
        for (int qb = 0; qb < 2; ++qb) {
            float ls = lsum[qb];
            ls += __shfl_xor(ls, 16, 64);
            ls += __shfl_xor(ls, 32, 64);
            float rinv[4];
#pragma unroll
            for (int r = 0; r < 4; ++r) rinv[r] = 1.f / __shfl(ls, l4 * 4 + r, 64);
#pragma unroll
            for (int f = 0; f < 4; ++f)
#pragma unroll
                for (int r = 0; r < 4; ++r)
                    o[(size_t)(b * 2048 + qrow0 + qb * 16 + l4 * 4 + r) * 1024 + h * 64 + f * 16 + l15]
                        = (bf16)(oacc[qb][f][r] * rinv[r]);
        }
    }
}

// ---------------------------------------------------------------------------
extern "C" void kernel_launch(void* const* d_in, const int* in_sizes, int n_in,
                              void* d_out, int out_size, void* d_ws, size_t ws_size,
                              hipStream_t stream)
{
    const float* x  = (const float*)d_in[0];
    // d_in[1] = causal mask, implemented in-kernel
    const float* Wq = (const float*)d_in[2];
    const float* bq = (const float*)d_in[3];
    const float* Wk = (const float*)d_in[4];
    const float* Wv = (const float*)d_in[5];
    const float* bv = (const float*)d_in[6];
    const float* Wo = (const float*)d_in[7];
    const float* bo = (const float*)d_in[8];
    float* out = (float*)d_out;

    const size_t M1 = 1024ull * 1024ull, M4 = 4ull * M1;
    bf16* base = (bf16*)d_ws;
    bf16* xb  = base;              // 4M; dead after qkv -> ao aliases it
    bf16* wqb = base + M4;
    bf16* wkb = base + M4 + M1;
    bf16* wvb = base + M4 + 2 * M1;
    bf16* wob = base + M4 + 3 * M1;
    bf16* q   = base + 8 * M1;
    bf16* k   = base + 12 * M1;
    bf16* vt  = base + 16 * M1;    // written transposed by qkv
    bf16* ao  = xb;

    convert_kernel<<<4096, 256, 0, stream>>>(x, Wq, Wk, Wv, Wo, base);
    qkv_kernel<<<dim3(32, 24), 256, 0, stream>>>(xb, wqb, bq, wkb, wvb, bv, q, k, vt);
    attn_kernel<<<dim3(32, 8), 256, 0, stream>>>(q, k, vt, ao);
    oproj_kernel<<<dim3(32, 8), 256, 0, stream>>>(ao, wob, bo, out);
}

// Round 2
// 199.476 us; speedup vs baseline: 1.0010x; 1.0010x over previous
//
#include <hip/hip_runtime.h>
#include <hip/hip_bf16.h>
#include <cmath>

typedef __bf16 bf16;
typedef __bf16 bf16x8 __attribute__((ext_vector_type(8)));
typedef __bf16 bf16x4 __attribute__((ext_vector_type(4)));
typedef float f32x4 __attribute__((ext_vector_type(4)));

#define QS 0.18033688f   // hd^-0.5 * log2(e), folded into Wq/bq

// async 16B global->LDS. LDS dest = wave-uniform base + lane*16.
__device__ __forceinline__ void load16_to_lds(const void* g, void* l) {
    __builtin_amdgcn_global_load_lds(
        (const __attribute__((address_space(1))) unsigned int*)g,
        (__attribute__((address_space(3))) unsigned int*)l, 16, 0, 0);
}

// ---------------------------------------------------------------------------
// f32 -> bf16 convert: [x(4M) | Wq(1M) | Wk(1M) | Wv(1M) | Wo(1M)] -> dst
// Wq segment is prescaled by QS (softmax scale folded into Q projection).
// ---------------------------------------------------------------------------
__global__ __launch_bounds__(256) void convert_kernel(
    const float* __restrict__ x,  const float* __restrict__ wq,
    const float* __restrict__ wk, const float* __restrict__ wv,
    const float* __restrict__ wo, bf16* __restrict__ dst)
{
    const size_t M1 = 1024ull * 1024ull, M4 = 4ull * M1;
    size_t i0 = ((size_t)blockIdx.x * 256 + threadIdx.x) * 8;
    const float* s;
    size_t off;
    float sc = 1.f;
    if      (i0 < M4)        { s = x;  off = i0; }
    else if (i0 < M4 + M1)   { s = wq; off = i0 - M4; sc = QS; }
    else if (i0 < M4 + 2*M1) { s = wk; off = i0 - M4 - M1; }
    else if (i0 < M4 + 3*M1) { s = wv; off = i0 - M4 - 2*M1; }
    else                     { s = wo; off = i0 - M4 - 3*M1; }
    float4 a = *(const float4*)(s + off);
    float4 b = *(const float4*)(s + off + 4);
    bf16x8 r = { (bf16)(a.x*sc), (bf16)(a.y*sc), (bf16)(a.z*sc), (bf16)(a.w*sc),
                 (bf16)(b.x*sc), (bf16)(b.y*sc), (bf16)(b.z*sc), (bf16)(b.w*sc) };
    *(bf16x8*)(dst + i0) = r;
}

// ---------------------------------------------------------------------------
// bf16 GEMM, m97 structure: BK=32, 16B global_load_lds, XOR-swizzled LDS.
// BM=128: 4 waves 2x2 of 64x64 (acc[4][4]); BM=64: 2x2 of 32x64 (acc[2][4]).
// ---------------------------------------------------------------------------
template<int BM, bool OUT_F32>
__device__ __forceinline__ void gemm_core(
    const bf16* __restrict__ A, const bf16* __restrict__ W,
    const float* __restrict__ bias, void* __restrict__ C,
    int mb, int nb, bool vt_out, float bias_scale)
{
    constexpr int IF = BM / 32;
    __shared__ __align__(16) bf16 As[BM * 32];
    __shared__ __align__(16) bf16 Bs[128 * 32];

    const int tid  = threadIdx.x;
    const int lane = tid & 63;
    const int wave = tid >> 6;
    const int wr   = (wave >> 1) * (BM / 2);
    const int wc   = (wave & 1) * 64;
    const int l15  = lane & 15;
    const int l4   = lane >> 4;
    const int swz  = (l4 ^ ((l15 >> 1) & 3)) * 8;   // swizzled read column

    f32x4 acc[IF][4] = {};

    for (int kt = 0; kt < 32; ++kt) {
#pragma unroll
        for (int it = 0; it < BM / 64; ++it) {
            int c = it * 256 + tid;
            int scol = ((c & 3) ^ ((c >> 3) & 3)) * 8;
            load16_to_lds(&A[(size_t)(mb * BM + (c >> 2)) * 1024 + kt * 32 + scol],
                          &As[(it * 256 + (tid & 192)) * 8]);
        }
#pragma unroll
        for (int it = 0; it < 2; ++it) {
            int c = it * 256 + tid;
            int scol = ((c & 3) ^ ((c >> 3) & 3)) * 8;
            load16_to_lds(&W[(size_t)(nb * 128 + (c >> 2)) * 1024 + kt * 32 + scol],
                          &Bs[(it * 256 + (tid & 192)) * 8]);
        }
        __syncthreads();
        bf16x8 af[IF], bfr[4];
#pragma unroll
        for (int i = 0; i < IF; ++i)
            af[i] = *(const bf16x8*)&As[(wr + i * 16 + l15) * 32 + swz];
#pragma unroll
        for (int j = 0; j < 4; ++j)
            bfr[j] = *(const bf16x8*)&Bs[(wc + j * 16 + l15) * 32 + swz];
#pragma unroll
        for (int i = 0; i < IF; ++i)
#pragma unroll
            for (int j = 0; j < 4; ++j)
                acc[i][j] = __builtin_amdgcn_mfma_f32_16x16x32_bf16(
                    af[i], bfr[j], acc[i][j], 0, 0, 0);
        __syncthreads();
    }

    if (!OUT_F32 && vt_out) {
        // V output transposed: vt[(b*16+h)*64+d][s]
#pragma unroll
        for (int j = 0; j < 4; ++j) {
            int col = nb * 128 + wc + j * 16 + l15;
            float bv = bias ? bias[col] : 0.f;
            int h = col >> 6, d = col & 63;
#pragma unroll
            for (int i = 0; i < IF; ++i) {
                int m0 = mb * BM + wr + i * 16 + l4 * 4;
                int b = m0 >> 11, s = m0 & 2047;
                bf16x4 pk = { (bf16)(acc[i][j][0] + bv), (bf16)(acc[i][j][1] + bv),
                              (bf16)(acc[i][j][2] + bv), (bf16)(acc[i][j][3] + bv) };
                *(bf16x4*)&((bf16*)C)[(size_t)((b * 16 + h) * 64 + d) * 2048 + s] = pk;
            }
        }
    } else {
#pragma unroll
        for (int j = 0; j < 4; ++j) {
            int col = nb * 128 + wc + j * 16 + l15;
            float bv = bias ? bias[col] * bias_scale : 0.f;
#pragma unroll
            for (int i = 0; i < IF; ++i) {
                int row0 = mb * BM + wr + i * 16 + l4 * 4;
#pragma unroll
                for (int r = 0; r < 4; ++r) {
                    float val = acc[i][j][r] + bv;
                    size_t idx = (size_t)(row0 + r) * 1024 + col;
                    if (OUT_F32) ((float*)C)[idx] = val;
                    else         ((bf16*)C)[idx]  = (bf16)val;
                }
            }
        }
    }
}

__global__ __launch_bounds__(256) void qkv_kernel(
    const bf16* __restrict__ xb,
    const bf16* __restrict__ wqb, const float* __restrict__ bq,
    const bf16* __restrict__ wkb,
    const bf16* __restrict__ wvb, const float* __restrict__ bv,
    bf16* __restrict__ q, bf16* __restrict__ k, bf16* __restrict__ vt)
{
    int mb = blockIdx.x;
    int nbg = blockIdx.y;
    int sel = nbg >> 3, nb = nbg & 7;
    const bf16* W = (sel == 0) ? wqb : ((sel == 1) ? wkb : wvb);
    const float* bias = (sel == 0) ? bq : ((sel == 2) ? bv : nullptr);
    bf16* C = (sel == 0) ? q : ((sel == 1) ? k : vt);
    gemm_core<128, false>(xb, W, bias, C, mb, nb, sel == 2,
                          sel == 0 ? QS : 1.f);
}

__global__ __launch_bounds__(256) void oproj_kernel(
    const bf16* __restrict__ ao, const bf16* __restrict__ wob,
    const float* __restrict__ bo, float* __restrict__ out)
{
    // BM=128: 2x MFMA per LDS fragment byte vs BM=64 (kept: helped in R1)
    gemm_core<128, true>(ao, wob, bo, out, blockIdx.x, blockIdx.y, false, 1.f);
}

// ---------------------------------------------------------------------------
// Flash attention, S^T form, fixed-max softmax (p = 2^s, scores bounded).
// Q prescaled (QS folded into Wq/bq).
//
// v3: keep v2's 2x amortization (128-row q-tiles, 32 q-rows/wave: each K/V
// LDS fragment read feeds TWO MFMAs), but UN-pair the q-tiles to restore
// 512 blocks (v2's pairing gave 256 blocks = 1 block/CU = no inter-block
// overlap of barrier/stage latency -> occupancy 9%, attn 65us).
// Grid = (32 bh, 16 y), qt = 15-y: heavy tiles dispatch first (LPT), light
// tiles backfill the tail. linear%8 == bh%8 keeps each (b,h)'s K/V in one
// XCD L2. 50 KB LDS -> up to 3 blocks/CU resident.
// Double-buffered, XOR-swizzled K/VT staging; mask only on last two tiles;
// fully-masked last tile skipped per-wave; l-sum deferred to epilogue.
// ---------------------------------------------------------------------------
__global__ __launch_bounds__(256) void attn_kernel(
    const bf16* __restrict__ q, const bf16* __restrict__ k,
    const bf16* __restrict__ vt, bf16* __restrict__ o)
{
    __shared__ __align__(16) bf16 Ks[2][64 * 64];   // [key][d] swizzled
    __shared__ __align__(16) bf16 Vs[2][64 * 64];   // [d][key] swizzled
    __shared__ __align__(16) bf16 Ps[4][32 * 72];   // per-wave [q][key], stride 72

    const int tid  = threadIdx.x;
    const int lane = tid & 63;
    const int wave = tid >> 6;
    const int l15  = lane & 15;
    const int l4   = lane >> 4;

    const int bh = blockIdx.x;               // fast dim -> XCD = bh % 8
    const int qt = 15 - blockIdx.y;          // heavy-first (LPT) dispatch
    const int b = bh >> 4, h = bh & 15;

    auto stage = [&](int nt, int buf) {
#pragma unroll
        for (int it = 0; it < 2; ++it) {
            int c = it * 256 + tid;
            int scol = ((c & 7) ^ ((c >> 3) & 7)) * 8;
            load16_to_lds(&k[(size_t)(b * 2048 + nt * 64 + (c >> 3)) * 1024 + h * 64 + scol],
                          &Ks[buf][(it * 256 + (tid & 192)) * 8]);
            load16_to_lds(&vt[(size_t)(bh * 64 + (c >> 3)) * 2048 + nt * 64 + scol],
                          &Vs[buf][(it * 256 + (tid & 192)) * 8]);
        }
    };

    int b0 = 0;
    stage(0, 0);

    const int qrow0 = qt * 128 + wave * 32;     // wave's first q row
    bf16x8 qf[2][2];
#pragma unroll
    for (int qb = 0; qb < 2; ++qb)
#pragma unroll
        for (int kk = 0; kk < 2; ++kk)
            qf[qb][kk] = *(const bf16x8*)&q[(size_t)(b * 2048 + qrow0 + qb * 16 + l15) * 1024
                                           + h * 64 + kk * 32 + l4 * 8];

    f32x4 oacc[2][4] = {};
    float lsum[2] = { 0.f, 0.f };

    const int n = 2 * qt + 2;
    for (int nt = 0; nt < n; ++nt) {
        __syncthreads();                        // stage(nt) drained
        if (nt + 1 < n) stage(nt + 1, b0 ^ 1);

        // per-wave skip: tile entirely above the causal diagonal
        if (nt * 64 > qrow0 + 31) { b0 ^= 1; continue; }

        // St[key][q] = K · Q^T, two q-fragments per K-fragment read
        f32x4 s[2][4] = {};
#pragma unroll
        for (int kk = 0; kk < 2; ++kk) {
#pragma unroll
            for (int j = 0; j < 4; ++j) {
                bf16x8 kf = *(const bf16x8*)&Ks[b0][(j * 16 + l15) * 64
                                + (((kk * 4 + l4) ^ (l15 & 7)) * 8)];
                s[0][j] = __builtin_amdgcn_mfma_f32_16x16x32_bf16(kf, qf[0][kk], s[0][j], 0, 0, 0);
                s[1][j] = __builtin_amdgcn_mfma_f32_16x16x32_bf16(kf, qf[1][kk], s[1][j], 0, 0, 0);
            }
        }

        // fixed-max: p = 2^s; mask only where the tile crosses the diagonal
        const bool diag = (nt >= 2 * qt);
#pragma unroll
        for (int qb = 0; qb < 2; ++qb) {
            float pv[4][4];
            if (diag) {
                int qg = qrow0 + qb * 16 + l15;
#pragma unroll
                for (int j = 0; j < 4; ++j)
#pragma unroll
                    for (int r = 0; r < 4; ++r) {
                        int kg = nt * 64 + j * 16 + l4 * 4 + r;
                        pv[j][r] = (kg > qg) ? 0.f : __builtin_amdgcn_exp2f(s[qb][j][r]);
                    }
            } else {
#pragma unroll
                for (int j = 0; j < 4; ++j)
#pragma unroll
                    for (int r = 0; r < 4; ++r)
                        pv[j][r] = __builtin_amdgcn_exp2f(s[qb][j][r]);
            }
#pragma unroll
            for (int j = 0; j < 4; ++j)
                lsum[qb] += (pv[j][0] + pv[j][1]) + (pv[j][2] + pv[j][3]);

            // P^T (C-layout) -> Ps[q][key] (A-layout); wave-private
#pragma unroll
            for (int j = 0; j < 4; ++j) {
                bf16x4 pk = { (bf16)pv[j][0], (bf16)pv[j][1], (bf16)pv[j][2], (bf16)pv[j][3] };
                *(bf16x4*)&Ps[wave][(qb * 16 + l15) * 72 + j * 16 + l4 * 4] = pk;
            }
        }

        // O += P · V, two P-fragments per V-fragment read
#pragma unroll
        for (int kk = 0; kk < 2; ++kk) {
            bf16x8 pf0 = *(const bf16x8*)&Ps[wave][l15 * 72 + kk * 32 + l4 * 8];
            bf16x8 pf1 = *(const bf16x8*)&Ps[wave][(16 + l15) * 72 + kk * 32 + l4 * 8];
#pragma unroll
            for (int f = 0; f < 4; ++f) {
                bf16x8 vf = *(const bf16x8*)&Vs[b0][(f * 16 + l15) * 64
                                + (((kk * 4 + l4) ^ (l15 & 7)) * 8)];
                oacc[0][f] = __builtin_amdgcn_mfma_f32_16x16x32_bf16(pf0, vf, oacc[0][f], 0, 0, 0);
                oacc[1][f] = __builtin_amdgcn_mfma_f32_16x16x32_bf16(pf1, vf, oacc[1][f], 0, 0, 0);
            }
        }
        b0 ^= 1;
    }

    // epilogue: reduce l across the 4 l4-groups, divide, store
#pragma unroll
    for (int qb = 0; qb < 2; ++qb) {
        float ls = lsum[qb];
        ls += __shfl_xor(ls, 16, 64);
        ls += __shfl_xor(ls, 32, 64);
        float rinv[4];
#pragma unroll
        for (int r = 0; r < 4; ++r) rinv[r] = 1.f / __shfl(ls, l4 * 4 + r, 64);
#pragma unroll
        for (int f = 0; f < 4; ++f)
#pragma unroll
            for (int r = 0; r < 4; ++r)
                o[(size_t)(b * 2048 + qrow0 + qb * 16 + l4 * 4 + r) * 1024 + h * 64 + f * 16 + l15]
                    = (bf16)(oacc[qb][f][r] * rinv[r]);
    }
}

// ---------------------------------------------------------------------------
extern "C" void kernel_launch(void* const* d_in, const int* in_sizes, int n_in,
                              void* d_out, int out_size, void* d_ws, size_t ws_size,
                              hipStream_t stream)
{
    const float* x  = (const float*)d_in[0];
    // d_in[1] = causal mask, implemented in-kernel
    const float* Wq = (const float*)d_in[2];
    const float* bq = (const float*)d_in[3];
    const float* Wk = (const float*)d_in[4];
    const float* Wv = (const float*)d_in[5];
    const float* bv = (const float*)d_in[6];
    const float* Wo = (const float*)d_in[7];
    const float* bo = (const float*)d_in[8];
    float* out = (float*)d_out;

    const size_t M1 = 1024ull * 1024ull, M4 = 4ull * M1;
    bf16* base = (bf16*)d_ws;
    bf16* xb  = base;              // 4M; dead after qkv -> ao aliases it
    bf16* wqb = base + M4;
    bf16* wkb = base + M4 + M1;
    bf16* wvb = base + M4 + 2 * M1;
    bf16* wob = base + M4 + 3 * M1;
    bf16* q   = base + 8 * M1;
    bf16* k   = base + 12 * M1;
    bf16* vt  = base + 16 * M1;    // written transposed by qkv
    bf16* ao  = xb;

    convert_kernel<<<4096, 256, 0, stream>>>(x, Wq, Wk, Wv, Wo, base);
    qkv_kernel<<<dim3(32, 24), 256, 0, stream>>>(xb, wqb, bq, wkb, wvb, bv, q, k, vt);
    attn_kernel<<<dim3(32, 16), 256, 0, stream>>>(q, k, vt, ao);
    oproj_kernel<<<dim3(32, 8), 256, 0, stream>>>(ao, wob, bo, out);
}

// Round 3
// 193.326 us; speedup vs baseline: 1.0329x; 1.0318x over previous
//
#include <hip/hip_runtime.h>
#include <hip/hip_bf16.h>
#include <cmath>

typedef __bf16 bf16;
typedef __bf16 bf16x8 __attribute__((ext_vector_type(8)));
typedef __bf16 bf16x4 __attribute__((ext_vector_type(4)));
typedef float f32x4 __attribute__((ext_vector_type(4)));

#define QS 0.18033688f   // hd^-0.5 * log2(e), folded into Wq/bq

// async 16B global->LDS. LDS dest = wave-uniform base + lane*16.
__device__ __forceinline__ void load16_to_lds(const void* g, void* l) {
    __builtin_amdgcn_global_load_lds(
        (const __attribute__((address_space(1))) unsigned int*)g,
        (__attribute__((address_space(3))) unsigned int*)l, 16, 0, 0);
}

// ---------------------------------------------------------------------------
// f32 -> bf16 convert: [x(4M) | Wq(1M) | Wk(1M) | Wv(1M) | Wo(1M)] -> dst
// Wq segment is prescaled by QS (softmax scale folded into Q projection).
// ---------------------------------------------------------------------------
__global__ __launch_bounds__(256) void convert_kernel(
    const float* __restrict__ x,  const float* __restrict__ wq,
    const float* __restrict__ wk, const float* __restrict__ wv,
    const float* __restrict__ wo, bf16* __restrict__ dst)
{
    const size_t M1 = 1024ull * 1024ull, M4 = 4ull * M1;
    size_t i0 = ((size_t)blockIdx.x * 256 + threadIdx.x) * 8;
    const float* s;
    size_t off;
    float sc = 1.f;
    if      (i0 < M4)        { s = x;  off = i0; }
    else if (i0 < M4 + M1)   { s = wq; off = i0 - M4; sc = QS; }
    else if (i0 < M4 + 2*M1) { s = wk; off = i0 - M4 - M1; }
    else if (i0 < M4 + 3*M1) { s = wv; off = i0 - M4 - 2*M1; }
    else                     { s = wo; off = i0 - M4 - 3*M1; }
    float4 a = *(const float4*)(s + off);
    float4 b = *(const float4*)(s + off + 4);
    bf16x8 r = { (bf16)(a.x*sc), (bf16)(a.y*sc), (bf16)(a.z*sc), (bf16)(a.w*sc),
                 (bf16)(b.x*sc), (bf16)(b.y*sc), (bf16)(b.z*sc), (bf16)(b.w*sc) };
    *(bf16x8*)(dst + i0) = r;
}

// ---------------------------------------------------------------------------
// bf16 GEMM, m97 structure: BK=32, 16B global_load_lds, XOR-swizzled LDS.
// BM=128: 4 waves 2x2 of 64x64 (acc[4][4]).
// ---------------------------------------------------------------------------
template<int BM, bool OUT_F32>
__device__ __forceinline__ void gemm_core(
    const bf16* __restrict__ A, const bf16* __restrict__ W,
    const float* __restrict__ bias, void* __restrict__ C,
    int mb, int nb, bool vt_out, float bias_scale)
{
    constexpr int IF = BM / 32;
    __shared__ __align__(16) bf16 As[BM * 32];
    __shared__ __align__(16) bf16 Bs[128 * 32];

    const int tid  = threadIdx.x;
    const int lane = tid & 63;
    const int wave = tid >> 6;
    const int wr   = (wave >> 1) * (BM / 2);
    const int wc   = (wave & 1) * 64;
    const int l15  = lane & 15;
    const int l4   = lane >> 4;
    const int swz  = (l4 ^ ((l15 >> 1) & 3)) * 8;   // swizzled read column

    f32x4 acc[IF][4] = {};

    for (int kt = 0; kt < 32; ++kt) {
#pragma unroll
        for (int it = 0; it < BM / 64; ++it) {
            int c = it * 256 + tid;
            int scol = ((c & 3) ^ ((c >> 3) & 3)) * 8;
            load16_to_lds(&A[(size_t)(mb * BM + (c >> 2)) * 1024 + kt * 32 + scol],
                          &As[(it * 256 + (tid & 192)) * 8]);
        }
#pragma unroll
        for (int it = 0; it < 2; ++it) {
            int c = it * 256 + tid;
            int scol = ((c & 3) ^ ((c >> 3) & 3)) * 8;
            load16_to_lds(&W[(size_t)(nb * 128 + (c >> 2)) * 1024 + kt * 32 + scol],
                          &Bs[(it * 256 + (tid & 192)) * 8]);
        }
        __syncthreads();
        bf16x8 af[IF], bfr[4];
#pragma unroll
        for (int i = 0; i < IF; ++i)
            af[i] = *(const bf16x8*)&As[(wr + i * 16 + l15) * 32 + swz];
#pragma unroll
        for (int j = 0; j < 4; ++j)
            bfr[j] = *(const bf16x8*)&Bs[(wc + j * 16 + l15) * 32 + swz];
#pragma unroll
        for (int i = 0; i < IF; ++i)
#pragma unroll
            for (int j = 0; j < 4; ++j)
                acc[i][j] = __builtin_amdgcn_mfma_f32_16x16x32_bf16(
                    af[i], bfr[j], acc[i][j], 0, 0, 0);
        __syncthreads();
    }

    if (!OUT_F32 && vt_out) {
        // V output transposed: vt[(b*16+h)*64+d][s]
#pragma unroll
        for (int j = 0; j < 4; ++j) {
            int col = nb * 128 + wc + j * 16 + l15;
            float bv = bias ? bias[col] : 0.f;
            int h = col >> 6, d = col & 63;
#pragma unroll
            for (int i = 0; i < IF; ++i) {
                int m0 = mb * BM + wr + i * 16 + l4 * 4;
                int b = m0 >> 11, s = m0 & 2047;
                bf16x4 pk = { (bf16)(acc[i][j][0] + bv), (bf16)(acc[i][j][1] + bv),
                              (bf16)(acc[i][j][2] + bv), (bf16)(acc[i][j][3] + bv) };
                *(bf16x4*)&((bf16*)C)[(size_t)((b * 16 + h) * 64 + d) * 2048 + s] = pk;
            }
        }
    } else {
#pragma unroll
        for (int j = 0; j < 4; ++j) {
            int col = nb * 128 + wc + j * 16 + l15;
            float bv = bias ? bias[col] * bias_scale : 0.f;
#pragma unroll
            for (int i = 0; i < IF; ++i) {
                int row0 = mb * BM + wr + i * 16 + l4 * 4;
#pragma unroll
                for (int r = 0; r < 4; ++r) {
                    float val = acc[i][j][r] + bv;
                    size_t idx = (size_t)(row0 + r) * 1024 + col;
                    if (OUT_F32) ((float*)C)[idx] = val;
                    else         ((bf16*)C)[idx]  = (bf16)val;
                }
            }
        }
    }
}

__global__ __launch_bounds__(256) void qkv_kernel(
    const bf16* __restrict__ xb,
    const bf16* __restrict__ wqb, const float* __restrict__ bq,
    const bf16* __restrict__ wkb,
    const bf16* __restrict__ wvb, const float* __restrict__ bv,
    bf16* __restrict__ q, bf16* __restrict__ k, bf16* __restrict__ vt)
{
    int mb = blockIdx.x;
    int nbg = blockIdx.y;
    int sel = nbg >> 3, nb = nbg & 7;
    const bf16* W = (sel == 0) ? wqb : ((sel == 1) ? wkb : wvb);
    const float* bias = (sel == 0) ? bq : ((sel == 2) ? bv : nullptr);
    bf16* C = (sel == 0) ? q : ((sel == 1) ? k : vt);
    gemm_core<128, false>(xb, W, bias, C, mb, nb, sel == 2,
                          sel == 0 ? QS : 1.f);
}

__global__ __launch_bounds__(256) void oproj_kernel(
    const bf16* __restrict__ ao, const bf16* __restrict__ wob,
    const float* __restrict__ bo, float* __restrict__ out)
{
    gemm_core<128, true>(ao, wob, bo, out, blockIdx.x, blockIdx.y, false, 1.f);
}

// ---------------------------------------------------------------------------
// Flash attention, S^T form, fixed-max softmax (p = 2^s, scores bounded).
// Q prescaled (QS folded into Wq/bq).
//
// v4: occupancy-first. Three rounds triangulate time ~ 1/(waves per CU)
// (v1: 8 w/CU -> 41us; v3: ~4.6 -> 54; v2: 4 -> 65): the kernel is
// latency-bound on the per-wave chain, so the lever is concurrent waves.
// Block = 2 waves (128 thr) owning a 64-row q-tile (32 rows/wave, keeping
// the 2-fragment amortization: each K/V LDS read feeds 2 MFMAs).
// Grid (32 bh, 32 qt) = 1024 blocks = 4/CU; LDS 41.2KB -> 3 resident
// -> 6 waves/CU (vs v3's ~4.6 avg), with fine-grained LPT backfill
// (qt = 31-y: heavy 32-iter blocks dispatch first).
// linear%8 == bh%8 keeps each (b,h)'s K/V in one XCD L2.
// Double-buffered, XOR-swizzled K/VT staging; diag mask only on nt==qt;
// l-sum deferred to epilogue.
// ---------------------------------------------------------------------------
__global__ __launch_bounds__(128) void attn_kernel(
    const bf16* __restrict__ q, const bf16* __restrict__ k,
    const bf16* __restrict__ vt, bf16* __restrict__ o)
{
    __shared__ __align__(16) bf16 Ks[2][64 * 64];   // [key][d] swizzled
    __shared__ __align__(16) bf16 Vs[2][64 * 64];   // [d][key] swizzled
    __shared__ __align__(16) bf16 Ps[2][32 * 72];   // per-wave [q][key], stride 72

    const int tid  = threadIdx.x;
    const int lane = tid & 63;
    const int wave = tid >> 6;                // 0..1
    const int l15  = lane & 15;
    const int l4   = lane >> 4;

    const int bh = blockIdx.x;               // fast dim -> XCD = bh % 8
    const int qt = 31 - blockIdx.y;          // heavy-first (LPT) dispatch
    const int b = bh >> 4, h = bh & 15;

    auto stage = [&](int nt, int buf) {
#pragma unroll
        for (int it = 0; it < 4; ++it) {
            int c = it * 128 + tid;           // 0..511: row=c>>3, 16B unit=c&7
            int scol = ((c & 7) ^ ((c >> 3) & 7)) * 8;
            load16_to_lds(&k[(size_t)(b * 2048 + nt * 64 + (c >> 3)) * 1024 + h * 64 + scol],
                          &Ks[buf][(it * 128 + (tid & 64)) * 8]);
            load16_to_lds(&vt[(size_t)(bh * 64 + (c >> 3)) * 2048 + nt * 64 + scol],
                          &Vs[buf][(it * 128 + (tid & 64)) * 8]);
        }
    };

    int b0 = 0;
    stage(0, 0);

    const int qrow0 = qt * 64 + wave * 32;      // wave's first q row
    bf16x8 qf[2][2];
#pragma unroll
    for (int qb = 0; qb < 2; ++qb)
#pragma unroll
        for (int kk = 0; kk < 2; ++kk)
            qf[qb][kk] = *(const bf16x8*)&q[(size_t)(b * 2048 + qrow0 + qb * 16 + l15) * 1024
                                           + h * 64 + kk * 32 + l4 * 8];

    f32x4 oacc[2][4] = {};
    float lsum[2] = { 0.f, 0.f };

    const int n = qt + 1;
    for (int nt = 0; nt < n; ++nt) {
        __syncthreads();                        // stage(nt) drained
        if (nt + 1 < n) stage(nt + 1, b0 ^ 1);

        // St[key][q] = K · Q^T, two q-fragments per K-fragment read
        f32x4 s[2][4] = {};
#pragma unroll
        for (int kk = 0; kk < 2; ++kk) {
#pragma unroll
            for (int j = 0; j < 4; ++j) {
                bf16x8 kf = *(const bf16x8*)&Ks[b0][(j * 16 + l15) * 64
                                + (((kk * 4 + l4) ^ (l15 & 7)) * 8)];
                s[0][j] = __builtin_amdgcn_mfma_f32_16x16x32_bf16(kf, qf[0][kk], s[0][j], 0, 0, 0);
                s[1][j] = __builtin_amdgcn_mfma_f32_16x16x32_bf16(kf, qf[1][kk], s[1][j], 0, 0, 0);
            }
        }

        // fixed-max: p = 2^s; mask only on the diagonal tile
        const bool diag = (nt == qt);
#pragma unroll
        for (int qb = 0; qb < 2; ++qb) {
            float pv[4][4];
            if (diag) {
                int qg = qrow0 + qb * 16 + l15;
#pragma unroll
                for (int j = 0; j < 4; ++j)
#pragma unroll
                    for (int r = 0; r < 4; ++r) {
                        int kg = nt * 64 + j * 16 + l4 * 4 + r;
                        pv[j][r] = (kg > qg) ? 0.f : __builtin_amdgcn_exp2f(s[qb][j][r]);
                    }
            } else {
#pragma unroll
                for (int j = 0; j < 4; ++j)
#pragma unroll
                    for (int r = 0; r < 4; ++r)
                        pv[j][r] = __builtin_amdgcn_exp2f(s[qb][j][r]);
            }
#pragma unroll
            for (int j = 0; j < 4; ++j)
                lsum[qb] += (pv[j][0] + pv[j][1]) + (pv[j][2] + pv[j][3]);

            // P^T (C-layout) -> Ps[q][key] (A-layout); wave-private
#pragma unroll
            for (int j = 0; j < 4; ++j) {
                bf16x4 pk = { (bf16)pv[j][0], (bf16)pv[j][1], (bf16)pv[j][2], (bf16)pv[j][3] };
                *(bf16x4*)&Ps[wave][(qb * 16 + l15) * 72 + j * 16 + l4 * 4] = pk;
            }
        }

        // O += P · V, two P-fragments per V-fragment read
#pragma unroll
        for (int kk = 0; kk < 2; ++kk) {
            bf16x8 pf0 = *(const bf16x8*)&Ps[wave][l15 * 72 + kk * 32 + l4 * 8];
            bf16x8 pf1 = *(const bf16x8*)&Ps[wave][(16 + l15) * 72 + kk * 32 + l4 * 8];
#pragma unroll
            for (int f = 0; f < 4; ++f) {
                bf16x8 vf = *(const bf16x8*)&Vs[b0][(f * 16 + l15) * 64
                                + (((kk * 4 + l4) ^ (l15 & 7)) * 8)];
                oacc[0][f] = __builtin_amdgcn_mfma_f32_16x16x32_bf16(pf0, vf, oacc[0][f], 0, 0, 0);
                oacc[1][f] = __builtin_amdgcn_mfma_f32_16x16x32_bf16(pf1, vf, oacc[1][f], 0, 0, 0);
            }
        }
        b0 ^= 1;
    }

    // epilogue: reduce l across the 4 l4-groups, divide, store
#pragma unroll
    for (int qb = 0; qb < 2; ++qb) {
        float ls = lsum[qb];
        ls += __shfl_xor(ls, 16, 64);
        ls += __shfl_xor(ls, 32, 64);
        float rinv[4];
#pragma unroll
        for (int r = 0; r < 4; ++r) rinv[r] = 1.f / __shfl(ls, l4 * 4 + r, 64);
#pragma unroll
        for (int f = 0; f < 4; ++f)
#pragma unroll
            for (int r = 0; r < 4; ++r)
                o[(size_t)(b * 2048 + qrow0 + qb * 16 + l4 * 4 + r) * 1024 + h * 64 + f * 16 + l15]
                    = (bf16)(oacc[qb][f][r] * rinv[r]);
    }
}

// ---------------------------------------------------------------------------
extern "C" void kernel_launch(void* const* d_in, const int* in_sizes, int n_in,
                              void* d_out, int out_size, void* d_ws, size_t ws_size,
                              hipStream_t stream)
{
    const float* x  = (const float*)d_in[0];
    // d_in[1] = causal mask, implemented in-kernel
    const float* Wq = (const float*)d_in[2];
    const float* bq = (const float*)d_in[3];
    const float* Wk = (const float*)d_in[4];
    const float* Wv = (const float*)d_in[5];
    const float* bv = (const float*)d_in[6];
    const float* Wo = (const float*)d_in[7];
    const float* bo = (const float*)d_in[8];
    float* out = (float*)d_out;

    const size_t M1 = 1024ull * 1024ull, M4 = 4ull * M1;
    bf16* base = (bf16*)d_ws;
    bf16* xb  = base;              // 4M; dead after qkv -> ao aliases it
    bf16* wqb = base + M4;
    bf16* wkb = base + M4 + M1;
    bf16* wvb = base + M4 + 2 * M1;
    bf16* wob = base + M4 + 3 * M1;
    bf16* q   = base + 8 * M1;
    bf16* k   = base + 12 * M1;
    bf16* vt  = base + 16 * M1;    // written transposed by qkv
    bf16* ao  = xb;

    convert_kernel<<<4096, 256, 0, stream>>>(x, Wq, Wk, Wv, Wo, base);
    qkv_kernel<<<dim3(32, 24), 256, 0, stream>>>(xb, wqb, bq, wkb, wvb, bv, q, k, vt);
    attn_kernel<<<dim3(32, 32), 128, 0, stream>>>(q, k, vt, ao);
    oproj_kernel<<<dim3(32, 8), 256, 0, stream>>>(ao, wob, bo, out);
}